// Round 14
// baseline (961.230 us; speedup 1.0000x reference)
//
#include <hip/hip_runtime.h>

#define TT 64
#define BB 256
#define HH 1024
#define ZZ 512
#define EE 32

#define NKB0 33   // K=1056 in 32-deep blocks (layer0: h 32 blocks + x 1 block)
#define NKB1 64   // K=2048
#define NKBZ 16   // K=512
#define NKBP 32   // K=1024

#define SLOTSH ((size_t)(HH / 16) * BB * 16)   // shorts per tiled h slot = 262144 (512 KB)

typedef __attribute__((ext_vector_type(8))) short short8;
typedef __attribute__((ext_vector_type(4))) float f4;

__device__ __forceinline__ f4 mfma16(short8 a, short8 b, f4 c) {
  return __builtin_amdgcn_mfma_f32_16x16x32_bf16(a, b, c, 0, 0, 0);
}

__device__ __forceinline__ unsigned short f2bf(float f) {
  unsigned u = __builtin_bit_cast(unsigned, f);
  u = u + 0x7fffu + ((u >> 16) & 1u);   // RNE; inputs are finite
  return (unsigned short)(u >> 16);
}

__device__ __forceinline__ float sigm(float x) { return 1.0f / (1.0f + __expf(-x)); }
__device__ __forceinline__ float tanh_f(float x) { return 1.0f - 2.0f / (__expf(2.0f * x) + 1.0f); }

__device__ __forceinline__ short8 ld16(const short* p) { return *(const short8*)p; }

// Agent-scope relaxed 16B load as 2x8B atomics -> global_load_dwordx2 sc1
// (L2-bypass, device-coherent, vmcnt-tracked so the compiler can pipeline it).
__device__ __forceinline__ short8 ld16_byp(const short* p) {
  union { unsigned long long u[2]; short8 v; } t;
  t.u[0] = __hip_atomic_load((const unsigned long long*)p, __ATOMIC_RELAXED, __HIP_MEMORY_SCOPE_AGENT);
  t.u[1] = __hip_atomic_load((const unsigned long long*)p + 1, __ATOMIC_RELAXED, __HIP_MEMORY_SCOPE_AGENT);
  return t.v;
}

// sc1 write-through dword store (no L2 dirty allocation -> no wbl2 needed; value
// is at LLC once vmcnt retires -- mechanism validated by R4/R6).
__device__ __forceinline__ void st4_byp(short* p, unsigned v) {
  __hip_atomic_store((unsigned*)p, v, __ATOMIC_RELAXED, __HIP_MEMORY_SCOPE_AGENT);
}

// FLAT per-btile barrier: 64 WGs/group, 8 leaves (one per 8 jt), each WG incs
// its leaf once per gen; waiters poll all 8 leaf lines (parallel loads) until
// min >= gen*8. Removes the root+flag chain (~2 LLC RTTs) of the tree version.
// Release = s_waitcnt vmcnt(0) (cross-WG h data is sc1 write-through).
__device__ __forceinline__ void btile_barrier(unsigned* bar, int btid, int jt, unsigned gen) {
  asm volatile("s_waitcnt vmcnt(0)" ::: "memory");  // sc1 stores at LLC
  __syncthreads();
  if (threadIdx.x == 0) {
    unsigned* base = bar + btid * (8 * 32);
    __hip_atomic_fetch_add(base + (jt >> 3) * 32, 1u, __ATOMIC_RELAXED, __HIP_MEMORY_SCOPE_AGENT);
    for (;;) {
      unsigned m = 0xffffffffu;
      #pragma unroll
      for (int i = 0; i < 8; ++i) {
        const unsigned v = __hip_atomic_load(base + i * 32, __ATOMIC_RELAXED, __HIP_MEMORY_SCOPE_AGENT);
        m = v < m ? v : m;
      }
      if (m >= gen * 8u) break;
      __builtin_amdgcn_s_sleep(1);
    }
  }
  __syncthreads();
}

// ---------------- pack: weights -> bf16 MFMA-fragment order, inputs -> bf16 ----------------
__global__ void pack_all(
    const float* __restrict__ z, const float* __restrict__ tg,
    const float* __restrict__ Wih0, const float* __restrict__ Whh0,
    const float* __restrict__ Wih1, const float* __restrict__ Whh1,
    const float* __restrict__ Wz0, const float* __restrict__ Wz1,
    const float* __restrict__ Wp,
    short* __restrict__ W0P, short* __restrict__ W1P,
    short* __restrict__ WzP, short* __restrict__ WpP,
    short* __restrict__ zbf, short* __restrict__ Xbf)
{
  const int N0 = 64 * NKB0 * 4 * 64;
  const int N1 = 64 * NKB1 * 4 * 64;
  const int N2 = 32 * NKBZ * 4 * 64;
  const int N3 = NKBP * 2 * 64;
  const int N4 = (BB * ZZ) / 8;
  const int N5 = (TT * BB * EE) / 8;
  const int TOT = N0 + N1 + N2 + N3 + N4 + N5;
  for (int idx = blockIdx.x * blockDim.x + threadIdx.x; idx < TOT;
       idx += gridDim.x * blockDim.x) {
    int j = idx;
    short8 ov;
    if (j < N0) {
      const int l = j & 63, fc = (j >> 6) & 3, rest = j >> 8;
      const int kb = rest % NKB0, jt = rest / NKB0;
      const int row = fc * HH + jt * 16 + (l & 15);
      const int k0 = kb * 32 + ((l >> 4) * 8);
      #pragma unroll
      for (int i = 0; i < 8; ++i) {
        const int k = k0 + i;
        const float v = (k < HH) ? Whh0[(size_t)row * HH + k]
                                 : Wih0[(size_t)row * EE + (k - HH)];
        ov[i] = (short)f2bf(v);
      }
      *(short8*)(W0P + (size_t)j * 8) = ov;
      continue;
    }
    j -= N0;
    if (j < N1) {
      const int l = j & 63, fc = (j >> 6) & 3, rest = j >> 8;
      const int kb = rest & 63, jt = rest >> 6;
      const int row = fc * HH + jt * 16 + (l & 15);
      const int k0 = kb * 32 + ((l >> 4) * 8);
      #pragma unroll
      for (int i = 0; i < 8; ++i) {
        const int k = k0 + i;
        const float v = (k < HH) ? Wih1[(size_t)row * HH + k]
                                 : Whh1[(size_t)row * HH + (k - HH)];
        ov[i] = (short)f2bf(v);
      }
      *(short8*)(W1P + (size_t)j * 8) = ov;
      continue;
    }
    j -= N1;
    if (j < N2) {
      const int l = j & 63, fc = (j >> 6) & 3, rest = j >> 8;
      const int kb = rest & 15, ct = rest >> 4;
      const int col = ct * 64 + fc * 16 + (l & 15);
      const int lay = col >> 10, ch = col & (HH - 1);
      const int k0 = kb * 32 + ((l >> 4) * 8);
      const float* W = lay ? Wz1 : Wz0;
      #pragma unroll
      for (int i = 0; i < 8; ++i) ov[i] = (short)f2bf(W[(size_t)ch * ZZ + k0 + i]);
      *(short8*)(WzP + (size_t)j * 8) = ov;
      continue;
    }
    j -= N2;
    if (j < N3) {
      const int l = j & 63, fc = (j >> 6) & 1, kb = j >> 7;
      const int e = fc * 16 + (l & 15);
      const int k0 = kb * 32 + ((l >> 4) * 8);
      #pragma unroll
      for (int i = 0; i < 8; ++i) ov[i] = (short)f2bf(Wp[(size_t)e * HH + k0 + i]);
      *(short8*)(WpP + (size_t)j * 8) = ov;
      continue;
    }
    j -= N3;
    if (j < N4) {
      #pragma unroll
      for (int i = 0; i < 8; ++i) ov[i] = (short)f2bf(z[(size_t)j * 8 + i]);
      *(short8*)(zbf + (size_t)j * 8) = ov;
      continue;
    }
    j -= N4;
    {
      const int base = j * 8;
      const int t = base >> 13, rem = base & 8191;
      if (t == 0) {
        #pragma unroll
        for (int i = 0; i < 8; ++i) ov[i] = 0;
      } else {
        #pragma unroll
        for (int i = 0; i < 8; ++i) ov[i] = (short)f2bf(tg[(size_t)(t - 1) * 8192 + rem + i]);
      }
      *(short8*)(Xbf + (size_t)j * 8) = ov;
    }
  }
}

// ---------------- init: h0/h1 = tanh(z @ Wz^T + bz), written in tiled h layout ----------------
__global__ void __launch_bounds__(256, 1)
init_h(const short* __restrict__ WzP, const short* __restrict__ zbf,
       const float* __restrict__ bz0, const float* __restrict__ bz1,
       short* __restrict__ H0s0, short* __restrict__ H1s0)
{
  __shared__ float red[2][64][66];
  const int wg = blockIdx.x;            // 128 = 4 btiles x 32 ctiles
  const int btile = (wg >> 5) * 64;
  const int ct = wg & 31;
  const int tid = threadIdx.x;
  const int wv = tid >> 6, ln = tid & 63;
  const int lr = ln & 15, lk = (ln >> 4) * 8, hi4 = (ln >> 4) * 4;

  f4 acc[4][4];
  #pragma unroll
  for (int r = 0; r < 4; ++r)
    #pragma unroll
    for (int c = 0; c < 4; ++c) acc[r][c] = (f4)0.0f;

  #pragma unroll 2
  for (int i = 0; i < 4; ++i) {
    const int kb = wv + i * 4;
    short8 av[4], bv[4];
    const short* ap = zbf + (size_t)(btile + lr) * ZZ + kb * 32 + lk;
    #pragma unroll
    for (int r = 0; r < 4; ++r) av[r] = ld16(ap + (size_t)r * 16 * ZZ);
    const short* bp = WzP + ((size_t)(ct * NKBZ + kb) * 4) * 512 + ln * 8;
    #pragma unroll
    for (int c = 0; c < 4; ++c) bv[c] = ld16(bp + (size_t)c * 512);
    #pragma unroll
    for (int r = 0; r < 4; ++r)
      #pragma unroll
      for (int c = 0; c < 4; ++c) acc[r][c] = mfma16(av[r], bv[c], acc[r][c]);
  }

  if (wv < 2) {
    #pragma unroll
    for (int r = 0; r < 4; ++r)
      #pragma unroll
      for (int c = 0; c < 4; ++c)
        #pragma unroll
        for (int q = 0; q < 4; ++q)
          red[wv][r * 16 + hi4 + q][c * 16 + lr] = acc[r][c][q];
  }
  __syncthreads();
  if (wv >= 2) {
    #pragma unroll
    for (int r = 0; r < 4; ++r)
      #pragma unroll
      for (int c = 0; c < 4; ++c)
        #pragma unroll
        for (int q = 0; q < 4; ++q)
          red[wv - 2][r * 16 + hi4 + q][c * 16 + lr] += acc[r][c][q];
  }
  __syncthreads();

  const int c2 = tid & 63, rr = tid >> 6;
  #pragma unroll
  for (int k = 0; k < 16; ++k) {
    const int r = rr + k * 4;
    const int cg = ct * 64 + c2;
    const int lay = cg >> 10, ch = cg & (HH - 1);
    const float v = tanh_f(red[0][r][c2] + red[1][r][c2] + (lay ? bz1[ch] : bz0[ch]));
    short* dst = lay ? H1s0 : H0s0;
    dst[(size_t)(ch >> 4) * (BB * 16) + (size_t)(btile + r) * 16 + (ch & 15)] = (short)f2bf(v);
  }
}

// ---------------- persistent sequential LSTM ----------------
// R13 champion + two cuts:
//  (1) FLAT leaf-poll barrier (arrive=1 atomic, wait=poll 8 leaf lines):
//      removes the root+flag serial chain (~2 LLC RTTs per step).
//  (2) Static-B register residency: W0's B fragments are step-invariant ->
//      keep kb-blocks i=0,1 (bw[2][4]) and the x-block B (bx[2]) in registers
//      for all 64 steps (40 VGPR, fits (512,1) budget).
template <bool BIG>
__global__ void __launch_bounds__(512, 1)
lstm_seq(const short* __restrict__ W0P, const short* __restrict__ W1P,
         const short* __restrict__ Xbf,
         short* __restrict__ H0, short* __restrict__ H1,
         short* __restrict__ H1a,
         const float* __restrict__ bi0, const float* __restrict__ bh0,
         const float* __restrict__ bi1, const float* __restrict__ bh1,
         unsigned* __restrict__ bar)
{
  __shared__ float red[4][64][68];      // [slot][gate-col][row pad 68] = 69.6 KB
  const int wg = blockIdx.x;            // 256 WGs
  const int x = wg & 7;
  const int q = wg >> 3;
  const int jt = x + 8 * (q & 7);       // 8 distinct jt per XCD
  const int btid = q >> 3;              // 0..3
  const int btile = btid * 64;
  const int tid = threadIdx.x;
  const int wv = tid >> 6, ln = tid & 63;          // 8 waves, K-split-8
  const int lr = ln & 15, lk = (ln >> 4) * 8, hi4 = (ln >> 4) * 4;

  const int u = tid & 15;
  const int rbase = tid >> 4;           // 0..31
  const int colg = jt * 16 + u;

  float bs0[4], bs1[4];
  #pragma unroll
  for (int g = 0; g < 4; ++g) {
    bs0[g] = bi0[g * HH + colg] + bh0[g * HH + colg];
    bs1[g] = bi1[g * HH + colg] + bh1[g * HH + colg];
  }

  const short* W0w = W0P + (size_t)jt * NKB0 * 4 * 512;
  const short* W1w = W1P + (size_t)jt * NKB1 * 4 * 512;

  // per-lane A offset within an h slot for k-block kb: slot + kb*2*4096 + aoff (+ r*256)
  const int aoff = (lk >> 4) * (BB * 16) + (btile + lr) * 16 + (lk & 15);
  const size_t ewi = (size_t)jt * (BB * 16) + u;   // elementwise tiled base

  float c0reg[2] = {0.0f, 0.0f}, c1reg[2] = {0.0f, 0.0f};   // C in registers

  // step-invariant W0 B fragments: kb-blocks i=0,1 + the x block (40 VGPR)
  short8 bw[2][4];
  #pragma unroll
  for (int i = 0; i < 2; ++i) {
    const short* bp = W0w + (size_t)(wv + 8 * i) * 4 * 512 + ln * 8;
    #pragma unroll
    for (int c = 0; c < 4; ++c) bw[i][c] = ld16(bp + (size_t)c * 512);
  }
  short8 bx[2];
  {
    const short* bp32 = W0w + (size_t)32 * 4 * 512 + ln * 8;
    #pragma unroll
    for (int p = 0; p < 2; ++p)
      bx[p] = ld16(bp32 + (size_t)((2 * wv + p) & 3) * 512);
  }

  for (int t = 0; t < TT; ++t) {
    const short* h0in = H0 + (size_t)(BIG ? t : (t & 1)) * SLOTSH;
    short* h0out      = H0 + (size_t)(BIG ? (t + 1) : ((t + 1) & 1)) * SLOTSH;
    const short* h1in = H1 + (size_t)(BIG ? t : (t & 1)) * SLOTSH;
    short* h1out      = H1 + (size_t)(BIG ? (t + 1) : ((t + 1) & 1)) * SLOTSH;

    // ===== GEMM0: gates0 = [h0 | x_t] @ W0^T, K-split over 8 waves =====
    f4 acc[4][4];
    #pragma unroll
    for (int r = 0; r < 4; ++r)
      #pragma unroll
      for (int c = 0; c < 4; ++c) acc[r][c] = (f4)0.0f;

    #pragma unroll
    for (int i = 0; i < 4; ++i) {
      const int kb = wv + 8 * i;        // 0..31 : h0 part (L2-warm: GEMM1(t-1) read it)
      short8 av[4], bv[4];
      const short* ap = h0in + (size_t)kb * 2 * (BB * 16) + aoff;
      #pragma unroll
      for (int r = 0; r < 4; ++r)
        av[r] = BIG ? ld16(ap + r * 256) : ld16_byp(ap + r * 256);
      if (i < 2) {
        #pragma unroll
        for (int c = 0; c < 4; ++c) bv[c] = bw[i][c];
      } else {
        const short* bp = W0w + (size_t)kb * 4 * 512 + ln * 8;
        #pragma unroll
        for (int c = 0; c < 4; ++c) bv[c] = ld16(bp + (size_t)c * 512);
      }
      #pragma unroll
      for (int r = 0; r < 4; ++r)
        #pragma unroll
        for (int c = 0; c < 4; ++c) acc[r][c] = mfma16(av[r], bv[c], acc[r][c]);
    }

    // kb = 32 : x_t part, distributed 2 MFMAs per wave (pair p = r*4+c,
    // wave = p>>1); B fragments register-resident (bx).
    {
      const short* xbase = Xbf + (size_t)((size_t)t * BB + btile + lr) * EE + lk;
      #pragma unroll
      for (int r = 0; r < 4; ++r)
        #pragma unroll
        for (int c = 0; c < 4; ++c)
          if (((r * 4 + c) >> 1) == wv) {
            const short8 av = ld16(xbase + (size_t)r * 16 * EE);
            acc[r][c] = mfma16(av, bx[(r * 4 + c) & 1], acc[r][c]);
          }
    }

    if (wv < 4) {
      #pragma unroll
      for (int r = 0; r < 4; ++r)
        #pragma unroll
        for (int c = 0; c < 4; ++c)
          *(f4*)&red[wv][c * 16 + lr][r * 16 + hi4] = acc[r][c];
    }
    __syncthreads();
    if (wv >= 4) {
      #pragma unroll
      for (int r = 0; r < 4; ++r)
        #pragma unroll
        for (int c = 0; c < 4; ++c) {
          f4* p = (f4*)&red[wv - 4][c * 16 + lr][r * 16 + hi4];
          f4 v = *p;
          v += acc[r][c];
          *p = v;
        }
    }
    __syncthreads();

    // fused LSTM elementwise, layer 0 (C in registers)
    #pragma unroll
    for (int k = 0; k < 2; ++k) {
      const int r = rbase + 32 * k;
      float s[4];
      #pragma unroll
      for (int g = 0; g < 4; ++g)
        s[g] = red[0][g * 16 + u][r] + red[1][g * 16 + u][r]
             + red[2][g * 16 + u][r] + red[3][g * 16 + u][r] + bs0[g];
      const float gi = sigm(s[0]), gf = sigm(s[1]);
      const float gg = tanh_f(s[2]), go = sigm(s[3]);
      c0reg[k] = gf * c0reg[k] + gi * gg;
      const unsigned hv = (unsigned)f2bf(go * tanh_f(c0reg[k]));
      const unsigned ov = (unsigned)__shfl_xor((int)hv, 1, 64);
      if ((tid & 1) == 0)
        st4_byp(h0out + ewi + (size_t)(btile + r) * 16, hv | (ov << 16));
    }

    // pre-barrier W1 first-kb B prefetch (static data; drains under the
    // barrier's release vmcnt(0), so GEMM1's first iteration starts hot)
    short8 bv0[4];
    {
      const short* bp0 = W1w + (size_t)wv * 4 * 512 + ln * 8;
      #pragma unroll
      for (int c = 0; c < 4; ++c) bv0[c] = ld16(bp0 + (size_t)c * 512);
    }

    btile_barrier(bar, btid, jt, (unsigned)(t + 1));

    // ===== GEMM1: gates1 = [h0' | h1] @ W1^T =====
    #pragma unroll
    for (int r = 0; r < 4; ++r)
      #pragma unroll
      for (int c = 0; c < 4; ++c) acc[r][c] = (f4)0.0f;

    // hoist h1-half A-loads (cold: last touched at ew1 of t-1) so their LLC
    // misses overlap the h0'-half compute below
    short8 a1[4][4];
    #pragma unroll
    for (int j = 0; j < 4; ++j) {
      const short* ap = h1in + (size_t)(wv + 8 * j) * 2 * (BB * 16) + aoff;
      #pragma unroll
      for (int r = 0; r < 4; ++r)
        a1[j][r] = BIG ? ld16(ap + r * 256) : ld16_byp(ap + r * 256);
    }

    #pragma unroll
    for (int i = 0; i < 4; ++i) {       // h0' half, kb = wv+8i in [0,32)
      const int kb = wv + 8 * i;
      short8 av[4], bv[4];
      const short* ap = h0out + (size_t)kb * 2 * (BB * 16) + aoff;
      #pragma unroll
      for (int r = 0; r < 4; ++r)
        av[r] = BIG ? ld16(ap + r * 256) : ld16_byp(ap + r * 256);
      if (i == 0) {
        #pragma unroll
        for (int c = 0; c < 4; ++c) bv[c] = bv0[c];
      } else {
        const short* bp = W1w + (size_t)kb * 4 * 512 + ln * 8;
        #pragma unroll
        for (int c = 0; c < 4; ++c) bv[c] = ld16(bp + (size_t)c * 512);
      }
      #pragma unroll
      for (int r = 0; r < 4; ++r)
        #pragma unroll
        for (int c = 0; c < 4; ++c) acc[r][c] = mfma16(av[r], bv[c], acc[r][c]);
    }
    #pragma unroll
    for (int j = 0; j < 4; ++j) {       // h1 half, kb = wv+8j+32, A from registers
      const int kb = wv + 8 * j + 32;
      short8 bv[4];
      const short* bp = W1w + (size_t)kb * 4 * 512 + ln * 8;
      #pragma unroll
      for (int c = 0; c < 4; ++c) bv[c] = ld16(bp + (size_t)c * 512);
      #pragma unroll
      for (int r = 0; r < 4; ++r)
        #pragma unroll
        for (int c = 0; c < 4; ++c) acc[r][c] = mfma16(a1[j][r], bv[c], acc[r][c]);
    }

    if (wv < 4) {
      #pragma unroll
      for (int r = 0; r < 4; ++r)
        #pragma unroll
        for (int c = 0; c < 4; ++c)
          *(f4*)&red[wv][c * 16 + lr][r * 16 + hi4] = acc[r][c];
    }
    __syncthreads();
    if (wv >= 4) {
      #pragma unroll
      for (int r = 0; r < 4; ++r)
        #pragma unroll
        for (int c = 0; c < 4; ++c) {
          f4* p = (f4*)&red[wv - 4][c * 16 + lr][r * 16 + hi4];
          f4 v = *p;
          v += acc[r][c];
          *p = v;
        }
    }
    __syncthreads();

    // fused LSTM elementwise, layer 1 (+ archive; BIG: h1out IS the archive slot)
    #pragma unroll
    for (int k = 0; k < 2; ++k) {
      const int r = rbase + 32 * k;
      float s[4];
      #pragma unroll
      for (int g = 0; g < 4; ++g)
        s[g] = red[0][g * 16 + u][r] + red[1][g * 16 + u][r]
             + red[2][g * 16 + u][r] + red[3][g * 16 + u][r] + bs1[g];
      const float gi = sigm(s[0]), gf = sigm(s[1]);
      const float gg = tanh_f(s[2]), go = sigm(s[3]);
      c1reg[k] = gf * c1reg[k] + gi * gg;
      const unsigned hv = (unsigned)f2bf(go * tanh_f(c1reg[k]));
      const unsigned ov = (unsigned)__shfl_xor((int)hv, 1, 64);
      if ((tid & 1) == 0) {
        const size_t ci = ewi + (size_t)(btile + r) * 16;
        const unsigned pv = hv | (ov << 16);
        st4_byp(h1out + ci, pv);
        if (!BIG) st4_byp(H1a + (size_t)t * SLOTSH + ci, pv);
      }
    }
    __syncthreads();   // protect `red` (next GEMM0 reduction) against stragglers
  }
}

// ---------------- final projection: out = H1 archive @ Wp^T + bp ----------------
__global__ void __launch_bounds__(256, 1)
proj(const short* __restrict__ H1a, const short* __restrict__ WpP,
     const float* __restrict__ bp, float* __restrict__ out)
{
  __shared__ float red[2][64][34];
  const int rt = blockIdx.x * 64;       // 256 blocks over 16384 rows
  const int tslot = rt >> 8;            // all 64 rows share one t (64 | 256)
  const int rb = rt & 255;
  const int tid = threadIdx.x;
  const int wv = tid >> 6, ln = tid & 63;
  const int lr = ln & 15, lk = (ln >> 4) * 8, hi4 = (ln >> 4) * 4;

  const short* base = H1a + (size_t)tslot * SLOTSH;
  const int aoff = (lk >> 4) * (BB * 16) + (rb + lr) * 16 + (lk & 15);

  f4 acc[4][2];
  #pragma unroll
  for (int r = 0; r < 4; ++r)
    #pragma unroll
    for (int c = 0; c < 2; ++c) acc[r][c] = (f4)0.0f;

  #pragma unroll 2
  for (int i = 0; i < 8; ++i) {
    const int kb = wv + i * 4;          // < 32
    short8 av[4], bv[2];
    const short* ap = base + (size_t)kb * 2 * (BB * 16) + aoff;
    #pragma unroll
    for (int r = 0; r < 4; ++r) av[r] = ld16(ap + r * 256);
    const short* bq = WpP + (size_t)kb * 2 * 512 + ln * 8;
    #pragma unroll
    for (int c = 0; c < 2; ++c) bv[c] = ld16(bq + (size_t)c * 512);
    #pragma unroll
    for (int r = 0; r < 4; ++r)
      #pragma unroll
      for (int c = 0; c < 2; ++c) acc[r][c] = mfma16(av[r], bv[c], acc[r][c]);
  }

  if (wv < 2) {
    #pragma unroll
    for (int r = 0; r < 4; ++r)
      #pragma unroll
      for (int c = 0; c < 2; ++c)
        #pragma unroll
        for (int q = 0; q < 4; ++q)
          red[wv][r * 16 + hi4 + q][c * 16 + lr] = acc[r][c][q];
  }
  __syncthreads();
  if (wv >= 2) {
    #pragma unroll
    for (int r = 0; r < 4; ++r)
      #pragma unroll
      for (int c = 0; c < 2; ++c)
        #pragma unroll
        for (int q = 0; q < 4; ++q)
          red[wv - 2][r * 16 + hi4 + q][c * 16 + lr] += acc[r][c][q];
  }
  __syncthreads();

  const int ce = tid & 31, rr = tid >> 5;
  #pragma unroll
  for (int k = 0; k < 8; ++k) {
    const int r = rr + k * 8;
    out[(size_t)(rt + r) * EE + ce] = red[0][r][ce] + red[1][r][ce] + bp[ce];
  }
}

extern "C" void kernel_launch(void* const* d_in, const int* in_sizes, int n_in,
                              void* d_out, int out_size, void* d_ws, size_t ws_size,
                              hipStream_t stream) {
  const float* z    = (const float*)d_in[0];
  const float* tg   = (const float*)d_in[1];
  const float* Wih0 = (const float*)d_in[3];
  const float* Whh0 = (const float*)d_in[4];
  const float* bi0  = (const float*)d_in[5];
  const float* bh0  = (const float*)d_in[6];
  const float* Wih1 = (const float*)d_in[7];
  const float* Whh1 = (const float*)d_in[8];
  const float* bi1  = (const float*)d_in[9];
  const float* bh1  = (const float*)d_in[10];
  const float* Wz0  = (const float*)d_in[11];
  const float* bz0  = (const float*)d_in[12];
  const float* Wz1  = (const float*)d_in[13];
  const float* bz1  = (const float*)d_in[14];
  const float* Wp   = (const float*)d_in[15];
  const float* bpv  = (const float*)d_in[16];

  char* ws = (char*)d_ws;
  size_t off = 0;
  unsigned* bar = (unsigned*)(ws + off); off += 8192;
  short* W0P  = (short*)(ws + off); off += (size_t)64 * NKB0 * 4 * 512 * 2;
  short* W1P  = (short*)(ws + off); off += (size_t)64 * NKB1 * 4 * 512 * 2;
  short* WzP  = (short*)(ws + off); off += (size_t)32 * NKBZ * 4 * 512 * 2;
  short* WpP  = (short*)(ws + off); off += (size_t)NKBP * 2 * 512 * 2;
  short* zbf  = (short*)(ws + off); off += (size_t)BB * ZZ * 2;
  short* Xbf  = (short*)(ws + off); off += (size_t)TT * BB * EE * 2;

  // BIG layout: H0seq (65 slots) + H1seq (65 slots, slots 1..64 = archive)
  const size_t seqB = (size_t)(TT + 1) * SLOTSH * 2;   // 34,078,720
  const size_t need_big = off + 2 * seqB;              // ~96 MB
  // small layout: H0pp(2) + H1pp(2) + H1a(64)
  const size_t need_small = off + 2 * ((size_t)2 * SLOTSH * 2) + (size_t)TT * SLOTSH * 2;
  const bool big = (ws_size >= need_big);

  if (ws_size < need_small) return;  // insufficient workspace -> fail loudly

  hipMemsetAsync(bar, 0, 8192, stream);

  pack_all<<<dim3(1024), dim3(256), 0, stream>>>(z, tg, Wih0, Whh0, Wih1, Whh1,
                                                 Wz0, Wz1, Wp,
                                                 W0P, W1P, WzP, WpP, zbf, Xbf);
  if (big) {
    short* H0seq = (short*)(ws + off);
    short* H1seq = (short*)(ws + off + seqB);
    init_h<<<dim3(128), dim3(256), 0, stream>>>(WzP, zbf, bz0, bz1, H0seq, H1seq);
    lstm_seq<true><<<dim3(256), dim3(512), 0, stream>>>(W0P, W1P, Xbf, H0seq, H1seq,
                                                        (short*)nullptr,
                                                        bi0, bh0, bi1, bh1, bar);
    proj<<<dim3(256), dim3(256), 0, stream>>>(H1seq + SLOTSH, WpP, bpv, (float*)d_out);
  } else {
    short* H0pp = (short*)(ws + off);
    short* H1pp = H0pp + 2 * SLOTSH;
    short* H1a  = H1pp + 2 * SLOTSH;
    init_h<<<dim3(128), dim3(256), 0, stream>>>(WzP, zbf, bz0, bz1, H0pp, H1pp);
    lstm_seq<false><<<dim3(256), dim3(512), 0, stream>>>(W0P, W1P, Xbf, H0pp, H1pp,
                                                         H1a,
                                                         bi0, bh0, bi1, bh1, bar);
    proj<<<dim3(256), dim3(256), 0, stream>>>(H1a, WpP, bpv, (float*)d_out);
  }
}

// Round 15
// 868.483 us; speedup vs baseline: 1.1068x; 1.1068x over previous
//
#include <hip/hip_runtime.h>

#define TT 64
#define BB 256
#define HH 1024
#define ZZ 512
#define EE 32

#define NKB0 33   // K=1056 in 32-deep blocks (layer0: h 32 blocks + x 1 block)
#define NKB1 64   // K=2048
#define NKBZ 16   // K=512
#define NKBP 32   // K=1024

#define SLOTSH ((size_t)(HH / 16) * BB * 16)   // shorts per tiled h slot = 262144 (512 KB)

typedef __attribute__((ext_vector_type(8))) short short8;
typedef __attribute__((ext_vector_type(4))) float f4;

__device__ __forceinline__ f4 mfma16(short8 a, short8 b, f4 c) {
  return __builtin_amdgcn_mfma_f32_16x16x32_bf16(a, b, c, 0, 0, 0);
}

__device__ __forceinline__ unsigned short f2bf(float f) {
  unsigned u = __builtin_bit_cast(unsigned, f);
  u = u + 0x7fffu + ((u >> 16) & 1u);   // RNE; inputs are finite
  return (unsigned short)(u >> 16);
}

__device__ __forceinline__ float sigm(float x) { return 1.0f / (1.0f + __expf(-x)); }
__device__ __forceinline__ float tanh_f(float x) { return 1.0f - 2.0f / (__expf(2.0f * x) + 1.0f); }

__device__ __forceinline__ short8 ld16(const short* p) { return *(const short8*)p; }

// Agent-scope relaxed 16B load as 2x8B atomics -> global_load_dwordx2 sc1
// (L2-bypass, device-coherent, vmcnt-tracked so the compiler can pipeline it).
__device__ __forceinline__ short8 ld16_byp(const short* p) {
  union { unsigned long long u[2]; short8 v; } t;
  t.u[0] = __hip_atomic_load((const unsigned long long*)p, __ATOMIC_RELAXED, __HIP_MEMORY_SCOPE_AGENT);
  t.u[1] = __hip_atomic_load((const unsigned long long*)p + 1, __ATOMIC_RELAXED, __HIP_MEMORY_SCOPE_AGENT);
  return t.v;
}

// sc1 write-through dword store (no L2 dirty allocation -> no wbl2 needed; value
// is at LLC once vmcnt retires -- mechanism validated by R4/R6).
__device__ __forceinline__ void st4_byp(short* p, unsigned v) {
  __hip_atomic_store((unsigned*)p, v, __ATOMIC_RELAXED, __HIP_MEMORY_SCOPE_AGENT);
}

// SPLIT per-btile tree barrier (64 WGs/group: 8 leaves x 8 + root + flag).
// arrive(): drain own sc1 stores, then leaf/root/flag increments -- no waiting.
// wait():   poll the flag, then __syncthreads.
// Work placed between arrive and wait overlaps the straggler window.
__device__ __forceinline__ void bar_arrive(unsigned* bar, int btid, int jt, unsigned gen) {
  asm volatile("s_waitcnt vmcnt(0)" ::: "memory");  // own sc1 stores at LLC
  __syncthreads();
  if (threadIdx.x == 0) {
    unsigned* base = bar + btid * (10 * 32);
    unsigned* leaf = base + (jt >> 3) * 32;
    unsigned prev = __hip_atomic_fetch_add(leaf, 1u, __ATOMIC_RELAXED, __HIP_MEMORY_SCOPE_AGENT);
    if (prev == gen * 8u - 1u) {
      unsigned rp = __hip_atomic_fetch_add(base + 8 * 32, 1u, __ATOMIC_RELAXED, __HIP_MEMORY_SCOPE_AGENT);
      if (rp == gen * 8u - 1u)
        __hip_atomic_store(base + 9 * 32, gen, __ATOMIC_RELAXED, __HIP_MEMORY_SCOPE_AGENT);
    }
  }
}

__device__ __forceinline__ void bar_wait(unsigned* bar, int btid, unsigned gen) {
  if (threadIdx.x == 0) {
    unsigned* flag = bar + btid * (10 * 32) + 9 * 32;
    while (__hip_atomic_load(flag, __ATOMIC_RELAXED, __HIP_MEMORY_SCOPE_AGENT) < gen)
      __builtin_amdgcn_s_sleep(1);
  }
  __syncthreads();
}

// ---------------- pack: weights -> bf16 MFMA-fragment order, inputs -> bf16 ----------------
__global__ void pack_all(
    const float* __restrict__ z, const float* __restrict__ tg,
    const float* __restrict__ Wih0, const float* __restrict__ Whh0,
    const float* __restrict__ Wih1, const float* __restrict__ Whh1,
    const float* __restrict__ Wz0, const float* __restrict__ Wz1,
    const float* __restrict__ Wp,
    short* __restrict__ W0P, short* __restrict__ W1P,
    short* __restrict__ WzP, short* __restrict__ WpP,
    short* __restrict__ zbf, short* __restrict__ Xbf)
{
  const int N0 = 64 * NKB0 * 4 * 64;
  const int N1 = 64 * NKB1 * 4 * 64;
  const int N2 = 32 * NKBZ * 4 * 64;
  const int N3 = NKBP * 2 * 64;
  const int N4 = (BB * ZZ) / 8;
  const int N5 = (TT * BB * EE) / 8;
  const int TOT = N0 + N1 + N2 + N3 + N4 + N5;
  for (int idx = blockIdx.x * blockDim.x + threadIdx.x; idx < TOT;
       idx += gridDim.x * blockDim.x) {
    int j = idx;
    short8 ov;
    if (j < N0) {
      const int l = j & 63, fc = (j >> 6) & 3, rest = j >> 8;
      const int kb = rest % NKB0, jt = rest / NKB0;
      const int row = fc * HH + jt * 16 + (l & 15);
      const int k0 = kb * 32 + ((l >> 4) * 8);
      #pragma unroll
      for (int i = 0; i < 8; ++i) {
        const int k = k0 + i;
        const float v = (k < HH) ? Whh0[(size_t)row * HH + k]
                                 : Wih0[(size_t)row * EE + (k - HH)];
        ov[i] = (short)f2bf(v);
      }
      *(short8*)(W0P + (size_t)j * 8) = ov;
      continue;
    }
    j -= N0;
    if (j < N1) {
      const int l = j & 63, fc = (j >> 6) & 3, rest = j >> 8;
      const int kb = rest & 63, jt = rest >> 6;
      const int row = fc * HH + jt * 16 + (l & 15);
      const int k0 = kb * 32 + ((l >> 4) * 8);
      #pragma unroll
      for (int i = 0; i < 8; ++i) {
        const int k = k0 + i;
        const float v = (k < HH) ? Wih1[(size_t)row * HH + k]
                                 : Whh1[(size_t)row * HH + (k - HH)];
        ov[i] = (short)f2bf(v);
      }
      *(short8*)(W1P + (size_t)j * 8) = ov;
      continue;
    }
    j -= N1;
    if (j < N2) {
      const int l = j & 63, fc = (j >> 6) & 3, rest = j >> 8;
      const int kb = rest & 15, ct = rest >> 4;
      const int col = ct * 64 + fc * 16 + (l & 15);
      const int lay = col >> 10, ch = col & (HH - 1);
      const int k0 = kb * 32 + ((l >> 4) * 8);
      const float* W = lay ? Wz1 : Wz0;
      #pragma unroll
      for (int i = 0; i < 8; ++i) ov[i] = (short)f2bf(W[(size_t)ch * ZZ + k0 + i]);
      *(short8*)(WzP + (size_t)j * 8) = ov;
      continue;
    }
    j -= N2;
    if (j < N3) {
      const int l = j & 63, fc = (j >> 6) & 1, kb = j >> 7;
      const int e = fc * 16 + (l & 15);
      const int k0 = kb * 32 + ((l >> 4) * 8);
      #pragma unroll
      for (int i = 0; i < 8; ++i) ov[i] = (short)f2bf(Wp[(size_t)e * HH + k0 + i]);
      *(short8*)(WpP + (size_t)j * 8) = ov;
      continue;
    }
    j -= N3;
    if (j < N4) {
      #pragma unroll
      for (int i = 0; i < 8; ++i) ov[i] = (short)f2bf(z[(size_t)j * 8 + i]);
      *(short8*)(zbf + (size_t)j * 8) = ov;
      continue;
    }
    j -= N4;
    {
      const int base = j * 8;
      const int t = base >> 13, rem = base & 8191;
      if (t == 0) {
        #pragma unroll
        for (int i = 0; i < 8; ++i) ov[i] = 0;
      } else {
        #pragma unroll
        for (int i = 0; i < 8; ++i) ov[i] = (short)f2bf(tg[(size_t)(t - 1) * 8192 + rem + i]);
      }
      *(short8*)(Xbf + (size_t)j * 8) = ov;
    }
  }
}

// ---------------- init: h0/h1 = tanh(z @ Wz^T + bz), written in tiled h layout ----------------
__global__ void __launch_bounds__(256, 1)
init_h(const short* __restrict__ WzP, const short* __restrict__ zbf,
       const float* __restrict__ bz0, const float* __restrict__ bz1,
       short* __restrict__ H0s0, short* __restrict__ H1s0)
{
  __shared__ float red[2][64][66];
  const int wg = blockIdx.x;            // 128 = 4 btiles x 32 ctiles
  const int btile = (wg >> 5) * 64;
  const int ct = wg & 31;
  const int tid = threadIdx.x;
  const int wv = tid >> 6, ln = tid & 63;
  const int lr = ln & 15, lk = (ln >> 4) * 8, hi4 = (ln >> 4) * 4;

  f4 acc[4][4];
  #pragma unroll
  for (int r = 0; r < 4; ++r)
    #pragma unroll
    for (int c = 0; c < 4; ++c) acc[r][c] = (f4)0.0f;

  #pragma unroll 2
  for (int i = 0; i < 4; ++i) {
    const int kb = wv + i * 4;
    short8 av[4], bv[4];
    const short* ap = zbf + (size_t)(btile + lr) * ZZ + kb * 32 + lk;
    #pragma unroll
    for (int r = 0; r < 4; ++r) av[r] = ld16(ap + (size_t)r * 16 * ZZ);
    const short* bp = WzP + ((size_t)(ct * NKBZ + kb) * 4) * 512 + ln * 8;
    #pragma unroll
    for (int c = 0; c < 4; ++c) bv[c] = ld16(bp + (size_t)c * 512);
    #pragma unroll
    for (int r = 0; r < 4; ++r)
      #pragma unroll
      for (int c = 0; c < 4; ++c) acc[r][c] = mfma16(av[r], bv[c], acc[r][c]);
  }

  if (wv < 2) {
    #pragma unroll
    for (int r = 0; r < 4; ++r)
      #pragma unroll
      for (int c = 0; c < 4; ++c)
        #pragma unroll
        for (int q = 0; q < 4; ++q)
          red[wv][r * 16 + hi4 + q][c * 16 + lr] = acc[r][c][q];
  }
  __syncthreads();
  if (wv >= 2) {
    #pragma unroll
    for (int r = 0; r < 4; ++r)
      #pragma unroll
      for (int c = 0; c < 4; ++c)
        #pragma unroll
        for (int q = 0; q < 4; ++q)
          red[wv - 2][r * 16 + hi4 + q][c * 16 + lr] += acc[r][c][q];
  }
  __syncthreads();

  const int c2 = tid & 63, rr = tid >> 6;
  #pragma unroll
  for (int k = 0; k < 16; ++k) {
    const int r = rr + k * 4;
    const int cg = ct * 64 + c2;
    const int lay = cg >> 10, ch = cg & (HH - 1);
    const float v = tanh_f(red[0][r][c2] + red[1][r][c2] + (lay ? bz1[ch] : bz0[ch]));
    short* dst = lay ? H1s0 : H0s0;
    dst[(size_t)(ch >> 4) * (BB * 16) + (size_t)(btile + r) * 16 + (ch & 15)] = (short)f2bf(v);
  }
}

// ---------------- persistent sequential LSTM ----------------
// R13 champion (256 WGs x 512 thr, K-split-8, 1 WG/CU, transposed b128
// reduction, distributed x-block, bv0 prefetch, tree per-btile barrier,
// C in regs) + ONE structural change:
//   SPLIT-PHASE BARRIER: arrive right after ew0's stores drain, then compute
//   the h1-half of GEMM1 (depends only on h1[t], synchronized by the PREVIOUS
//   step's barrier) while the flag propagates; wait for the flag only before
//   the h0'-half. The barrier straggler window absorbs ~40% of GEMM1.
template <bool BIG>
__global__ void __launch_bounds__(512, 1)
lstm_seq(const short* __restrict__ W0P, const short* __restrict__ W1P,
         const short* __restrict__ Xbf,
         short* __restrict__ H0, short* __restrict__ H1,
         short* __restrict__ H1a,
         const float* __restrict__ bi0, const float* __restrict__ bh0,
         const float* __restrict__ bi1, const float* __restrict__ bh1,
         unsigned* __restrict__ bar)
{
  __shared__ float red[4][64][68];      // [slot][gate-col][row pad 68] = 69.6 KB
  const int wg = blockIdx.x;            // 256 WGs
  const int x = wg & 7;
  const int q = wg >> 3;
  const int jt = x + 8 * (q & 7);       // 8 distinct jt per XCD
  const int btid = q >> 3;              // 0..3
  const int btile = btid * 64;
  const int tid = threadIdx.x;
  const int wv = tid >> 6, ln = tid & 63;          // 8 waves, K-split-8
  const int lr = ln & 15, lk = (ln >> 4) * 8, hi4 = (ln >> 4) * 4;

  const int u = tid & 15;
  const int rbase = tid >> 4;           // 0..31
  const int colg = jt * 16 + u;

  float bs0[4], bs1[4];
  #pragma unroll
  for (int g = 0; g < 4; ++g) {
    bs0[g] = bi0[g * HH + colg] + bh0[g * HH + colg];
    bs1[g] = bi1[g * HH + colg] + bh1[g * HH + colg];
  }

  const short* W0w = W0P + (size_t)jt * NKB0 * 4 * 512;
  const short* W1w = W1P + (size_t)jt * NKB1 * 4 * 512;

  // per-lane A offset within an h slot for k-block kb: slot + kb*2*4096 + aoff (+ r*256)
  const int aoff = (lk >> 4) * (BB * 16) + (btile + lr) * 16 + (lk & 15);
  const size_t ewi = (size_t)jt * (BB * 16) + u;   // elementwise tiled base

  float c0reg[2] = {0.0f, 0.0f}, c1reg[2] = {0.0f, 0.0f};   // C in registers

  for (int t = 0; t < TT; ++t) {
    const short* h0in = H0 + (size_t)(BIG ? t : (t & 1)) * SLOTSH;
    short* h0out      = H0 + (size_t)(BIG ? (t + 1) : ((t + 1) & 1)) * SLOTSH;
    const short* h1in = H1 + (size_t)(BIG ? t : (t & 1)) * SLOTSH;
    short* h1out      = H1 + (size_t)(BIG ? (t + 1) : ((t + 1) & 1)) * SLOTSH;

    // ===== GEMM0: gates0 = [h0 | x_t] @ W0^T, K-split over 8 waves =====
    f4 acc[4][4];
    #pragma unroll
    for (int r = 0; r < 4; ++r)
      #pragma unroll
      for (int c = 0; c < 4; ++c) acc[r][c] = (f4)0.0f;

    #pragma unroll
    for (int i = 0; i < 4; ++i) {
      const int kb = wv + 8 * i;        // 0..31 : h0 part (L2-warm: GEMM1(t-1) read it)
      short8 av[4], bv[4];
      const short* ap = h0in + (size_t)kb * 2 * (BB * 16) + aoff;
      #pragma unroll
      for (int r = 0; r < 4; ++r)
        av[r] = BIG ? ld16(ap + r * 256) : ld16_byp(ap + r * 256);
      const short* bp = W0w + (size_t)kb * 4 * 512 + ln * 8;
      #pragma unroll
      for (int c = 0; c < 4; ++c) bv[c] = ld16(bp + (size_t)c * 512);
      #pragma unroll
      for (int r = 0; r < 4; ++r)
        #pragma unroll
        for (int c = 0; c < 4; ++c) acc[r][c] = mfma16(av[r], bv[c], acc[r][c]);
    }

    // kb = 32 : x_t part, distributed 2 MFMAs per wave (pair p = r*4+c,
    // wave = p>>1). Indices compile-time constant; wv test is wave-uniform.
    {
      const short* xbase = Xbf + (size_t)((size_t)t * BB + btile + lr) * EE + lk;
      const short* bp32 = W0w + (size_t)32 * 4 * 512 + ln * 8;
      #pragma unroll
      for (int r = 0; r < 4; ++r)
        #pragma unroll
        for (int c = 0; c < 4; ++c)
          if (((r * 4 + c) >> 1) == wv) {
            const short8 av = ld16(xbase + (size_t)r * 16 * EE);
            const short8 bv = ld16(bp32 + (size_t)c * 512);
            acc[r][c] = mfma16(av, bv, acc[r][c]);
          }
    }

    if (wv < 4) {
      #pragma unroll
      for (int r = 0; r < 4; ++r)
        #pragma unroll
        for (int c = 0; c < 4; ++c)
          *(f4*)&red[wv][c * 16 + lr][r * 16 + hi4] = acc[r][c];
    }
    __syncthreads();
    if (wv >= 4) {
      #pragma unroll
      for (int r = 0; r < 4; ++r)
        #pragma unroll
        for (int c = 0; c < 4; ++c) {
          f4* p = (f4*)&red[wv - 4][c * 16 + lr][r * 16 + hi4];
          f4 v = *p;
          v += acc[r][c];
          *p = v;
        }
    }
    __syncthreads();

    // fused LSTM elementwise, layer 0 (C in registers)
    #pragma unroll
    for (int k = 0; k < 2; ++k) {
      const int r = rbase + 32 * k;
      float s[4];
      #pragma unroll
      for (int g = 0; g < 4; ++g)
        s[g] = red[0][g * 16 + u][r] + red[1][g * 16 + u][r]
             + red[2][g * 16 + u][r] + red[3][g * 16 + u][r] + bs0[g];
      const float gi = sigm(s[0]), gf = sigm(s[1]);
      const float gg = tanh_f(s[2]), go = sigm(s[3]);
      c0reg[k] = gf * c0reg[k] + gi * gg;
      const unsigned hv = (unsigned)f2bf(go * tanh_f(c0reg[k]));
      const unsigned ov = (unsigned)__shfl_xor((int)hv, 1, 64);
      if ((tid & 1) == 0)
        st4_byp(h0out + ewi + (size_t)(btile + r) * 16, hv | (ov << 16));
    }

    // pre-arrive W1 first-kb B prefetch (static; drains under arrive's vmcnt(0))
    short8 bv0[4];
    {
      const short* bp0 = W1w + (size_t)wv * 4 * 512 + ln * 8;
      #pragma unroll
      for (int c = 0; c < 4; ++c) bv0[c] = ld16(bp0 + (size_t)c * 512);
    }

    // ---- ARRIVE: own h0' stores at LLC, signal; do NOT wait yet ----
    bar_arrive(bar, btid, jt, (unsigned)(t + 1));

    // ===== GEMM1 h1-half (kb 32..63): depends only on h1[t], already
    // synchronized by the PREVIOUS step's barrier -> legal pre-wait work =====
    #pragma unroll
    for (int r = 0; r < 4; ++r)
      #pragma unroll
      for (int c = 0; c < 4; ++c) acc[r][c] = (f4)0.0f;

    short8 a1[4][4];
    #pragma unroll
    for (int j = 0; j < 4; ++j) {
      const short* ap = h1in + (size_t)(wv + 8 * j) * 2 * (BB * 16) + aoff;
      #pragma unroll
      for (int r = 0; r < 4; ++r)
        a1[j][r] = BIG ? ld16(ap + r * 256) : ld16_byp(ap + r * 256);
    }
    #pragma unroll
    for (int j = 0; j < 4; ++j) {       // kb = wv+8j+32
      const int kb = wv + 8 * j + 32;
      short8 bv[4];
      const short* bp = W1w + (size_t)kb * 4 * 512 + ln * 8;
      #pragma unroll
      for (int c = 0; c < 4; ++c) bv[c] = ld16(bp + (size_t)c * 512);
      #pragma unroll
      for (int r = 0; r < 4; ++r)
        #pragma unroll
        for (int c = 0; c < 4; ++c) acc[r][c] = mfma16(a1[j][r], bv[c], acc[r][c]);
    }

    // ---- WAIT: h0' of all btile peers now visible ----
    bar_wait(bar, btid, (unsigned)(t + 1));

    // ===== GEMM1 h0'-half (kb 0..31) =====
    #pragma unroll
    for (int i = 0; i < 4; ++i) {
      const int kb = wv + 8 * i;
      short8 av[4], bv[4];
      const short* ap = h0out + (size_t)kb * 2 * (BB * 16) + aoff;
      #pragma unroll
      for (int r = 0; r < 4; ++r)
        av[r] = BIG ? ld16(ap + r * 256) : ld16_byp(ap + r * 256);
      if (i == 0) {
        #pragma unroll
        for (int c = 0; c < 4; ++c) bv[c] = bv0[c];
      } else {
        const short* bp = W1w + (size_t)kb * 4 * 512 + ln * 8;
        #pragma unroll
        for (int c = 0; c < 4; ++c) bv[c] = ld16(bp + (size_t)c * 512);
      }
      #pragma unroll
      for (int r = 0; r < 4; ++r)
        #pragma unroll
        for (int c = 0; c < 4; ++c) acc[r][c] = mfma16(av[r], bv[c], acc[r][c]);
    }

    if (wv < 4) {
      #pragma unroll
      for (int r = 0; r < 4; ++r)
        #pragma unroll
        for (int c = 0; c < 4; ++c)
          *(f4*)&red[wv][c * 16 + lr][r * 16 + hi4] = acc[r][c];
    }
    __syncthreads();
    if (wv >= 4) {
      #pragma unroll
      for (int r = 0; r < 4; ++r)
        #pragma unroll
        for (int c = 0; c < 4; ++c) {
          f4* p = (f4*)&red[wv - 4][c * 16 + lr][r * 16 + hi4];
          f4 v = *p;
          v += acc[r][c];
          *p = v;
        }
    }
    __syncthreads();

    // fused LSTM elementwise, layer 1 (+ archive; BIG: h1out IS the archive slot)
    #pragma unroll
    for (int k = 0; k < 2; ++k) {
      const int r = rbase + 32 * k;
      float s[4];
      #pragma unroll
      for (int g = 0; g < 4; ++g)
        s[g] = red[0][g * 16 + u][r] + red[1][g * 16 + u][r]
             + red[2][g * 16 + u][r] + red[3][g * 16 + u][r] + bs1[g];
      const float gi = sigm(s[0]), gf = sigm(s[1]);
      const float gg = tanh_f(s[2]), go = sigm(s[3]);
      c1reg[k] = gf * c1reg[k] + gi * gg;
      const unsigned hv = (unsigned)f2bf(go * tanh_f(c1reg[k]));
      const unsigned ov = (unsigned)__shfl_xor((int)hv, 1, 64);
      if ((tid & 1) == 0) {
        const size_t ci = ewi + (size_t)(btile + r) * 16;
        const unsigned pv = hv | (ov << 16);
        st4_byp(h1out + ci, pv);
        if (!BIG) st4_byp(H1a + (size_t)t * SLOTSH + ci, pv);
      }
    }
    __syncthreads();   // protect `red` (next GEMM0 reduction) against stragglers
  }
}

// ---------------- final projection: out = H1 archive @ Wp^T + bp ----------------
__global__ void __launch_bounds__(256, 1)
proj(const short* __restrict__ H1a, const short* __restrict__ WpP,
     const float* __restrict__ bp, float* __restrict__ out)
{
  __shared__ float red[2][64][34];
  const int rt = blockIdx.x * 64;       // 256 blocks over 16384 rows
  const int tslot = rt >> 8;            // all 64 rows share one t (64 | 256)
  const int rb = rt & 255;
  const int tid = threadIdx.x;
  const int wv = tid >> 6, ln = tid & 63;
  const int lr = ln & 15, lk = (ln >> 4) * 8, hi4 = (ln >> 4) * 4;

  const short* base = H1a + (size_t)tslot * SLOTSH;
  const int aoff = (lk >> 4) * (BB * 16) + (rb + lr) * 16 + (lk & 15);

  f4 acc[4][2];
  #pragma unroll
  for (int r = 0; r < 4; ++r)
    #pragma unroll
    for (int c = 0; c < 2; ++c) acc[r][c] = (f4)0.0f;

  #pragma unroll 2
  for (int i = 0; i < 8; ++i) {
    const int kb = wv + i * 4;          // < 32
    short8 av[4], bv[2];
    const short* ap = base + (size_t)kb * 2 * (BB * 16) + aoff;
    #pragma unroll
    for (int r = 0; r < 4; ++r) av[r] = ld16(ap + r * 256);
    const short* bq = WpP + (size_t)kb * 2 * 512 + ln * 8;
    #pragma unroll
    for (int c = 0; c < 2; ++c) bv[c] = ld16(bq + (size_t)c * 512);
    #pragma unroll
    for (int r = 0; r < 4; ++r)
      #pragma unroll
      for (int c = 0; c < 2; ++c) acc[r][c] = mfma16(av[r], bv[c], acc[r][c]);
  }

  if (wv < 2) {
    #pragma unroll
    for (int r = 0; r < 4; ++r)
      #pragma unroll
      for (int c = 0; c < 2; ++c)
        #pragma unroll
        for (int q = 0; q < 4; ++q)
          red[wv][r * 16 + hi4 + q][c * 16 + lr] = acc[r][c][q];
  }
  __syncthreads();
  if (wv >= 2) {
    #pragma unroll
    for (int r = 0; r < 4; ++r)
      #pragma unroll
      for (int c = 0; c < 2; ++c)
        #pragma unroll
        for (int q = 0; q < 4; ++q)
          red[wv - 2][r * 16 + hi4 + q][c * 16 + lr] += acc[r][c][q];
  }
  __syncthreads();

  const int ce = tid & 31, rr = tid >> 5;
  #pragma unroll
  for (int k = 0; k < 8; ++k) {
    const int r = rr + k * 8;
    out[(size_t)(rt + r) * EE + ce] = red[0][r][ce] + red[1][r][ce] + bp[ce];
  }
}

extern "C" void kernel_launch(void* const* d_in, const int* in_sizes, int n_in,
                              void* d_out, int out_size, void* d_ws, size_t ws_size,
                              hipStream_t stream) {
  const float* z    = (const float*)d_in[0];
  const float* tg   = (const float*)d_in[1];
  const float* Wih0 = (const float*)d_in[3];
  const float* Whh0 = (const float*)d_in[4];
  const float* bi0  = (const float*)d_in[5];
  const float* bh0  = (const float*)d_in[6];
  const float* Wih1 = (const float*)d_in[7];
  const float* Whh1 = (const float*)d_in[8];
  const float* bi1  = (const float*)d_in[9];
  const float* bh1  = (const float*)d_in[10];
  const float* Wz0  = (const float*)d_in[11];
  const float* bz0  = (const float*)d_in[12];
  const float* Wz1  = (const float*)d_in[13];
  const float* bz1  = (const float*)d_in[14];
  const float* Wp   = (const float*)d_in[15];
  const float* bpv  = (const float*)d_in[16];

  char* ws = (char*)d_ws;
  size_t off = 0;
  unsigned* bar = (unsigned*)(ws + off); off += 8192;
  short* W0P  = (short*)(ws + off); off += (size_t)64 * NKB0 * 4 * 512 * 2;
  short* W1P  = (short*)(ws + off); off += (size_t)64 * NKB1 * 4 * 512 * 2;
  short* WzP  = (short*)(ws + off); off += (size_t)32 * NKBZ * 4 * 512 * 2;
  short* WpP  = (short*)(ws + off); off += (size_t)NKBP * 2 * 512 * 2;
  short* zbf  = (short*)(ws + off); off += (size_t)BB * ZZ * 2;
  short* Xbf  = (short*)(ws + off); off += (size_t)TT * BB * EE * 2;

  // BIG layout: H0seq (65 slots) + H1seq (65 slots, slots 1..64 = archive)
  const size_t seqB = (size_t)(TT + 1) * SLOTSH * 2;   // 34,078,720
  const size_t need_big = off + 2 * seqB;              // ~96 MB
  // small layout: H0pp(2) + H1pp(2) + H1a(64)
  const size_t need_small = off + 2 * ((size_t)2 * SLOTSH * 2) + (size_t)TT * SLOTSH * 2;
  const bool big = (ws_size >= need_big);

  if (ws_size < need_small) return;  // insufficient workspace -> fail loudly

  hipMemsetAsync(bar, 0, 8192, stream);

  pack_all<<<dim3(1024), dim3(256), 0, stream>>>(z, tg, Wih0, Whh0, Wih1, Whh1,
                                                 Wz0, Wz1, Wp,
                                                 W0P, W1P, WzP, WpP, zbf, Xbf);
  if (big) {
    short* H0seq = (short*)(ws + off);
    short* H1seq = (short*)(ws + off + seqB);
    init_h<<<dim3(128), dim3(256), 0, stream>>>(WzP, zbf, bz0, bz1, H0seq, H1seq);
    lstm_seq<true><<<dim3(256), dim3(512), 0, stream>>>(W0P, W1P, Xbf, H0seq, H1seq,
                                                        (short*)nullptr,
                                                        bi0, bh0, bi1, bh1, bar);
    proj<<<dim3(256), dim3(256), 0, stream>>>(H1seq + SLOTSH, WpP, bpv, (float*)d_out);
  } else {
    short* H0pp = (short*)(ws + off);
    short* H1pp = H0pp + 2 * SLOTSH;
    short* H1a  = H1pp + 2 * SLOTSH;
    init_h<<<dim3(128), dim3(256), 0, stream>>>(WzP, zbf, bz0, bz1, H0pp, H1pp);
    lstm_seq<false><<<dim3(256), dim3(512), 0, stream>>>(W0P, W1P, Xbf, H0pp, H1pp,
                                                         H1a,
                                                         bi0, bh0, bi1, bh1, bar);
    proj<<<dim3(256), dim3(256), 0, stream>>>(H1a, WpP, bpv, (float*)d_out);
  }
}